// Round 17
// baseline (291.325 us; speedup 1.0000x reference)
//
#include <hip/hip_runtime.h>
#include <math.h>

#define B_N 262144
#define K_N 100
#define D_N 384
#define EPS 1e-8f
#define MOM 0.95f
#define FLAG_THR 5e-4f       // 6.3 sigma of bf16-B gap error (std ~8e-5)
#define NBLK 256             // k_accum persistent blocks (1/CU)
#define ROWS_PB (B_N / NBLK) // 1024 rows per block
#define KSTR 101             // LDS sums k-stride: bank stride 5 -> conflict-free
#define PART_N (K_N * D_N)   // 38400

typedef __attribute__((ext_vector_type(8))) short short8;
typedef __attribute__((ext_vector_type(4))) float f32x4;

// workspace byte offsets
#define OFF_CPK   0          // 12*7*512 u16 = 86016 : B-hi packed [kk][nt][frag]
#define OFF_NC64  86016      // K f64
#define OFF_CNT   86816
#define OFF_FLAGN 87264
#define OFF_FLAGS 87328      // B u32 = 1048576
#define OFF_PARTS 1135904    // NBLK * 38400 i32 = 39321600

#define GLOAD_LDS(g, l) __builtin_amdgcn_global_load_lds( \
    (const __attribute__((address_space(1))) unsigned int*)(g), \
    (__attribute__((address_space(3))) unsigned int*)(l), 16, 0, 0)

// cpk u16 index for element (col, d): MFMA B-fragment order
__device__ __forceinline__ size_t cpk_idx(int col, int d) {
    int kk = d >> 5, r = d & 31, lg = r >> 3, j = r & 7;
    int nt = col >> 4, l15 = col & 15;
    return (size_t)((kk * 7 + nt) * 512) + lg * 128 + l15 * 8 + j;
}

__device__ __forceinline__ unsigned short bf16_rne(float x) {
    unsigned u = __float_as_uint(x);
    unsigned r = (u + 0x7fff + ((u >> 16) & 1)) >> 16;   // round-nearest-even
    return (unsigned short)r;
}

// ---- normalize centroids -> bf16 cpk; block 112 zeroes cnt/flagn ----
__global__ void k_norm_c(const float* __restrict__ c, unsigned short* __restrict__ cpk,
                         double* __restrict__ nc64, int* __restrict__ cnt,
                         int* __restrict__ flagn) {
    int col = blockIdx.x;
    int t = threadIdx.x;  // 128
    if (col == 112) {
        if (t < K_N) cnt[t] = 0;
        if (t == 0) *flagn = 0;
        return;
    }
    if (col >= K_N) {
        for (int d = t; d < D_N; d += 128) cpk[cpk_idx(col, d)] = 0;
        return;
    }
    const float* row = c + (size_t)col * D_N;
    double ss = 0.0;
    for (int d = t; d < D_N; d += 128) { double v = row[d]; ss += v * v; }
    __shared__ double red[2];
    for (int o = 32; o > 0; o >>= 1) ss += __shfl_down(ss, o);
    if ((t & 63) == 0) red[t >> 6] = ss;
    __syncthreads();
    double nc = fmax(sqrt(red[0] + red[1]), (double)EPS);
    if (t == 0) nc64[col] = nc;
    float inv = (float)(1.0 / nc);
    for (int d = t; d < D_N; d += 128)
        cpk[cpk_idx(col, d)] = bf16_rne(row[d] * inv);
}

// split 8 floats -> bf16 hi (trunc) + lo (rne of residual): a ≈ hi+lo to ~2^-17
__device__ __forceinline__ void splitA(float4 x0, float4 x1,
                                       short8& ah, short8& al, float& ss) {
    float xs[8] = {x0.x, x0.y, x0.z, x0.w, x1.x, x1.y, x1.z, x1.w};
#pragma unroll
    for (int j = 0; j < 8; j++) {
        float x = xs[j];
        unsigned xb = __float_as_uint(x);
        unsigned hb = xb & 0xffff0000u;
        float lf = x - __uint_as_float(hb);
        ah[j] = (short)(hb >> 16);
        al[j] = (short)bf16_rne(lf);
        ss = fmaf(x, x, ss);
    }
}

// ---- MFMA sims v9: 64-row block, FULL-ROW sequential A staging (reg->LDS),
// K-steps split across wave pairs, LDS acc merge. B tiles 0-4 LDS, 5-6 L2.
#define SA_STRIDE 1552       // 388 floats * 4 B (bank-stride 4 -> 2-way = free)
__global__ __launch_bounds__(512) void k_main(
    const float* __restrict__ e, const unsigned short* __restrict__ cpk,
    float* __restrict__ out_nov, float* __restrict__ out_cls,
    unsigned* __restrict__ flags, int* __restrict__ flagn) {
    __shared__ char smem[160768];
    float* sA = (float*)smem;                              // [64][388] f32
    unsigned short* sB = (unsigned short*)(smem + 99328);  // 60 x 1KB chunks
    float* mrg = (float*)smem;                             // alias, post-compute

    const int t = threadIdx.x;
    const int lane = t & 63;
    const int wid = t >> 6;                   // 8 waves
    const int l15 = lane & 15;
    const int lg = lane >> 4;
    const int rowbase = blockIdx.x * 64;

    // stage B tiles 0..4 (60 x 1KB chunks over 8 waves); LDS idx c = kk*5+nt
    for (int c = wid; c < 60; c += 8) {
        int kk = c / 5, nt = c - kk * 5;
        GLOAD_LDS((const char*)cpk + (size_t)(kk * 7 + nt) * 1024 + lane * 16,
                  (char*)sB + c * 1024);
    }

    // stage A: wave w -> rows 8w..8w+7, as 4 row-pairs; per pair 3 contiguous
    // 1KB loads (perfect coalescing + sequential DRAM) -> LDS row-major+pad
#pragma unroll
    for (int q = 0; q < 4; q++) {
        const char* gb = (const char*)e + ((size_t)(rowbase + wid * 8 + 2 * q)) * 1536;
#pragma unroll
        for (int i = 0; i < 3; i++) {
            int byt = i * 1024 + lane * 16;
            float4 v = *(const float4*)(gb + byt);
            int r = (byt >= 1536) ? 1 : 0;
            int off = byt - r * 1536;
            *(float4*)((char*)sA + (size_t)(wid * 8 + 2 * q + r) * SA_STRIDE + off) = v;
        }
    }
    __syncthreads();   // A + B resident

    f32x4 acc[7];
#pragma unroll
    for (int nt = 0; nt < 7; nt++) acc[nt] = f32x4{0.f, 0.f, 0.f, 0.f};
    float ss0 = 0.f;

    const int p = wid & 3;                    // row-group 0..3 (16 rows each)
    const int kk0 = (wid < 4) ? 0 : 6;        // K-split across wave pairs
    const int arow = p * 16 + l15;

#pragma unroll
    for (int u = 0; u < 6; u++) {
        const int kk = kk0 + u;
        const char* ap = (const char*)sA + (size_t)arow * SA_STRIDE + kk * 128 + lg * 32;
        float4 x0 = *(const float4*)ap;
        float4 x1 = *(const float4*)(ap + 16);
        short8 ah0, al0;
        splitA(x0, x1, ah0, al0, ss0);
#pragma unroll
        for (int nt = 0; nt < 5; nt++) {
            short8 bh = *(const short8*)(sB + (kk * 5 + nt) * 512 + lane * 8);
            acc[nt] = __builtin_amdgcn_mfma_f32_16x16x32_bf16(ah0, bh, acc[nt], 0, 0, 0);
            acc[nt] = __builtin_amdgcn_mfma_f32_16x16x32_bf16(al0, bh, acc[nt], 0, 0, 0);
        }
#pragma unroll
        for (int nt = 5; nt < 7; nt++) {      // tiles 5,6 from L2-hot global
            short8 bh = *(const short8*)(cpk + (kk * 7 + nt) * 512 + lane * 8);
            acc[nt] = __builtin_amdgcn_mfma_f32_16x16x32_bf16(ah0, bh, acc[nt], 0, 0, 0);
            acc[nt] = __builtin_amdgcn_mfma_f32_16x16x32_bf16(al0, bh, acc[nt], 0, 0, 0);
        }
    }
    __syncthreads();   // compute done; sA region reusable as merge scratch

    if (wid >= 4) {    // upper waves publish their half-K partials
        float* mb = mrg + ((size_t)(wid - 4) * 64 + lane) * 33;
#pragma unroll
        for (int nt = 0; nt < 7; nt++) {
            mb[nt * 4 + 0] = acc[nt][0]; mb[nt * 4 + 1] = acc[nt][1];
            mb[nt * 4 + 2] = acc[nt][2]; mb[nt * 4 + 3] = acc[nt][3];
        }
        mb[28] = ss0;
    }
    __syncthreads();
    if (wid >= 4) return;

    {
        const float* mb = mrg + ((size_t)wid * 64 + lane) * 33;
#pragma unroll
        for (int nt = 0; nt < 7; nt++) {
            acc[nt][0] += mb[nt * 4 + 0]; acc[nt][1] += mb[nt * 4 + 1];
            acc[nt][2] += mb[nt * 4 + 2]; acc[nt][3] += mb[nt * 4 + 3];
        }
        ss0 += mb[28];
    }

    // row sum-of-squares: lanes sharing l15 hold disjoint k-chunks
    ss0 += __shfl_xor(ss0, 16); ss0 += __shfl_xor(ss0, 32);
    const int rl = lg * 4 + (l15 & 3);
    float ssr0 = __shfl(ss0, rl);

    float b0 = -3e38f, b1 = -3e38f, b2 = -3e38f, b3 = -3e38f;
    float s0 = -3e38f, s1 = -3e38f, s2 = -3e38f, s3 = -3e38f;
    int i0 = 0, i1 = 0, i2 = 0, i3 = 0, j0 = 0, j1 = 0, j2 = 0, j3 = 0;
#pragma unroll
    for (int nt = 0; nt < 7; nt++) {
        int cl = nt * 16 + l15;
        bool valid = cl < K_N;
        float v;
        v = valid ? acc[nt][0] : -3e38f;
        if (v > b0) { s0 = b0; j0 = i0; b0 = v; i0 = cl; } else if (v > s0) { s0 = v; j0 = cl; }
        v = valid ? acc[nt][1] : -3e38f;
        if (v > b1) { s1 = b1; j1 = i1; b1 = v; i1 = cl; } else if (v > s1) { s1 = v; j1 = cl; }
        v = valid ? acc[nt][2] : -3e38f;
        if (v > b2) { s2 = b2; j2 = i2; b2 = v; i2 = cl; } else if (v > s2) { s2 = v; j2 = cl; }
        v = valid ? acc[nt][3] : -3e38f;
        if (v > b3) { s3 = b3; j3 = i3; b3 = v; i3 = cl; } else if (v > s3) { s3 = v; j3 = cl; }
    }
#pragma unroll
    for (int w = 1; w <= 8; w <<= 1) {
#define MRG(B, S, I, J)                                                        \
        {                                                                      \
            float ob = __shfl_xor(B, w), os = __shfl_xor(S, w);                \
            int obi = __shfl_xor(I, w), osi = __shfl_xor(J, w);                \
            if (ob > B) {                                                      \
                float ns; int nsi;                                             \
                if (B > os) { ns = B; nsi = I; } else { ns = os; nsi = osi; }  \
                B = ob; I = obi; S = ns; J = nsi;                              \
            } else if (ob > S) { S = ob; J = obi; }                            \
        }
        MRG(b0, s0, i0, j0) MRG(b1, s1, i1, j1) MRG(b2, s2, i2, j2) MRG(b3, s3, i3, j3)
#undef MRG
    }
    if (l15 < 4) {
        float bb = (l15 & 2) ? ((l15 & 1) ? b3 : b2) : ((l15 & 1) ? b1 : b0);
        float sv = (l15 & 2) ? ((l15 & 1) ? s3 : s2) : ((l15 & 1) ? s1 : s0);
        int bi   = (l15 & 2) ? ((l15 & 1) ? i3 : i2) : ((l15 & 1) ? i1 : i0);
        int si   = (l15 & 2) ? ((l15 & 1) ? j3 : j2) : ((l15 & 1) ? j1 : j0);
        int grow = rowbase + wid * 16 + rl;
        float nrm = fmaxf(sqrtf(ssr0), EPS);
        float msim = bb / nrm;
        out_nov[grow] = 1.f - msim * msim;
        out_cls[grow] = (float)bi;
        if (bb - sv < FLAG_THR * nrm) {   // near-tie: fp64 re-resolve later
            int pos = atomicAdd(flagn, 1);
            flags[pos] = ((unsigned)grow << 14) | ((unsigned)bi << 7) | (unsigned)si;
        }
    }
}

// ---- cooperative fp64 refinement of flagged near-ties ----
__global__ void k_refine(const float* __restrict__ e, const float* __restrict__ c_raw,
                         const double* __restrict__ nc64, const int* __restrict__ flagn,
                         const unsigned* __restrict__ flags,
                         float* __restrict__ out_nov, float* __restrict__ out_cls) {
    int n = *flagn;
    int gw = (blockIdx.x * 256 + threadIdx.x) >> 6;
    int lane = threadIdx.x & 63;
    int nw = (gridDim.x * 256) >> 6;
    for (int i = gw; i < n; i += nw) {
        unsigned f = flags[i];
        int row = f >> 14, bi = (f >> 7) & 127, si = f & 127;
        const float* er = e + (size_t)row * D_N;
        const float* ca = c_raw + (size_t)bi * D_N;
        const float* cb = c_raw + (size_t)si * D_N;
        double d1 = 0, d2 = 0, ee = 0;
#pragma unroll
        for (int j = 0; j < 6; j++) {
            int d = lane * 6 + j;
            double ev = er[d];
            d1 += ev * (double)ca[d];
            d2 += ev * (double)cb[d];
            ee += ev * ev;
        }
#pragma unroll
        for (int w = 1; w <= 32; w <<= 1) {
            d1 += __shfl_xor(d1, w); d2 += __shfl_xor(d2, w); ee += __shfl_xor(ee, w);
        }
        if (lane == 0) {
            double v1 = d1 / nc64[bi], v2 = d2 / nc64[si];
            int k; double v;
            if (v2 > v1 || (v2 == v1 && si < bi)) { k = si; v = v2; } else { k = bi; v = v1; }
            double nrm = fmax(sqrt(ee), (double)EPS);
            double ms = v / nrm;
            out_nov[row] = (float)(1.0 - ms * ms);
            out_cls[row] = (float)k;
        }
    }
}

// ---- streaming segment sums + histogram (post-refine assignments) ----
__global__ __launch_bounds__(768) void k_accum(
    const float* __restrict__ e, const float* __restrict__ cls,
    int* __restrict__ parts, int* __restrict__ cnt) {
    __shared__ int sums[D_N * KSTR];          // 155,136 B
    __shared__ int scls[ROWS_PB];             // 4 KB
    __shared__ int h[K_N];                    // 400 B
    const int t = threadIdx.x;
    const int rg = t / D_N;                   // 0..1 (row group)
    const int d = t - rg * D_N;               // owned dim
    const size_t rbase = (size_t)blockIdx.x * ROWS_PB;

    for (int i = t; i < D_N * KSTR; i += 768) sums[i] = 0;
    if (t < K_N) h[t] = 0;
    __syncthreads();
    for (int i = t; i < ROWS_PB; i += 768) {
        int k = (int)cls[rbase + i];
        scls[i] = k;
        atomicAdd(&h[k], 1);
    }
    __syncthreads();
    if (t < K_N && h[t] > 0) atomicAdd(&cnt[t], h[t]);

    const float* eb = e + rbase * D_N;
    for (int g = 0; g < ROWS_PB; g += 16) {
        const int r0 = g + rg,      r1 = g + rg + 2,  r2 = g + rg + 4,  r3 = g + rg + 6;
        const int r4 = g + rg + 8,  r5 = g + rg + 10, r6 = g + rg + 12, r7 = g + rg + 14;
        float v0 = eb[(size_t)r0 * D_N + d]; float v1 = eb[(size_t)r1 * D_N + d];
        float v2 = eb[(size_t)r2 * D_N + d]; float v3 = eb[(size_t)r3 * D_N + d];
        float v4 = eb[(size_t)r4 * D_N + d]; float v5 = eb[(size_t)r5 * D_N + d];
        float v6 = eb[(size_t)r6 * D_N + d]; float v7 = eb[(size_t)r7 * D_N + d];
        atomicAdd(&sums[d * KSTR + scls[r0]], __float2int_rn(v0 * 65536.f));
        atomicAdd(&sums[d * KSTR + scls[r1]], __float2int_rn(v1 * 65536.f));
        atomicAdd(&sums[d * KSTR + scls[r2]], __float2int_rn(v2 * 65536.f));
        atomicAdd(&sums[d * KSTR + scls[r3]], __float2int_rn(v3 * 65536.f));
        atomicAdd(&sums[d * KSTR + scls[r4]], __float2int_rn(v4 * 65536.f));
        atomicAdd(&sums[d * KSTR + scls[r5]], __float2int_rn(v5 * 65536.f));
        atomicAdd(&sums[d * KSTR + scls[r6]], __float2int_rn(v6 * 65536.f));
        atomicAdd(&sums[d * KSTR + scls[r7]], __float2int_rn(v7 * 65536.f));
    }
    __syncthreads();

    int* pb = parts + (size_t)blockIdx.x * PART_N;
    for (int i = t; i < PART_N; i += 768) {
        int kq = i / D_N, dr = i - kq * D_N;
        pb[i] = sums[dr * KSTR + kq];
    }
}

// ---- deterministic reduce: 256 i32 partials -> centroids (+ counts out) ----
__global__ void k_reduce(const float* __restrict__ c_raw, const int* __restrict__ parts,
                         const int* __restrict__ cnt, const float* __restrict__ counts_in,
                         float* __restrict__ out_cent, float* __restrict__ out_cnts) {
    int idx = blockIdx.x * 256 + threadIdx.x;
    if (blockIdx.x == 0 && threadIdx.x < K_N)
        out_cnts[threadIdx.x] = counts_in[threadIdx.x] + (float)cnt[threadIdx.x];
    if (idx >= PART_N) return;
    long long s = 0;
#pragma unroll 8
    for (int b = 0; b < NBLK; b++) s += (long long)parts[(size_t)b * PART_N + idx];
    int k = idx / D_N;
    int n = cnt[k];
    float c0 = c_raw[idx];
    float mean = (float)((double)s / 65536.0 / (double)(n > 1 ? n : 1));
    out_cent[idx] = (n > 0) ? (MOM * c0 + (1.0f - MOM) * mean) : c0;
}

extern "C" void kernel_launch(void* const* d_in, const int* in_sizes, int n_in,
                              void* d_out, int out_size, void* d_ws, size_t ws_size,
                              hipStream_t stream) {
    const float* emb    = (const float*)d_in[0];
    const float* cen    = (const float*)d_in[1];
    const float* counts = (const float*)d_in[2];
    float* out = (float*)d_out;
    char* ws = (char*)d_ws;

    unsigned short* cpk   = (unsigned short*)(ws + OFF_CPK);
    double*         nc64  = (double*)(ws + OFF_NC64);
    int*            cnt   = (int*)(ws + OFF_CNT);
    int*            flagn = (int*)(ws + OFF_FLAGN);
    unsigned*       flags = (unsigned*)(ws + OFF_FLAGS);
    int*            parts = (int*)(ws + OFF_PARTS);

    float* out_nov  = out;
    float* out_cls  = out + B_N;
    float* out_cent = out + 2 * B_N;
    float* out_cnts = out + 2 * B_N + K_N * D_N;

    k_norm_c<<<113, 128, 0, stream>>>(cen, cpk, nc64, cnt, flagn);
    k_main<<<B_N / 64, 512, 0, stream>>>(emb, cpk, out_nov, out_cls, flags, flagn);
    k_refine<<<256, 256, 0, stream>>>(emb, cen, nc64, flagn, flags, out_nov, out_cls);
    k_accum<<<NBLK, 768, 0, stream>>>(emb, out_cls, parts, cnt);
    k_reduce<<<(PART_N + 255) / 256, 256, 0, stream>>>(cen, parts, cnt, counts,
                                                       out_cent, out_cnts);
}

// Round 18
// 257.983 us; speedup vs baseline: 1.1292x; 1.1292x over previous
//
#include <hip/hip_runtime.h>
#include <math.h>

#define B_N 262144
#define K_N 100
#define D_N 384
#define EPS 1e-8f
#define MOM 0.95f
#define FLAG_THR 5e-4f       // 6.3 sigma of bf16-B gap error (std ~8e-5)
#define NBLK 256             // k_accum persistent blocks (1/CU)
#define ROWS_PB (B_N / NBLK) // 1024 rows per block
#define KSTR 101             // LDS sums k-stride: bank stride 5 -> conflict-free
#define PART_N (K_N * D_N)   // 38400

typedef __attribute__((ext_vector_type(8))) short short8;
typedef __attribute__((ext_vector_type(4))) float f32x4;

// workspace byte offsets
#define OFF_CPK   0          // 12*7*512 u16 = 86016 : B-hi packed [kk][nt][frag]
#define OFF_NC64  86016      // K f64
#define OFF_CNT   86816
#define OFF_FLAGN 87264
#define OFF_FLAGS 87328      // B u32 = 1048576
#define OFF_PARTS 1135904    // NBLK * 38400 i32 = 39321600

#define GLOAD_LDS(g, l) __builtin_amdgcn_global_load_lds( \
    (const __attribute__((address_space(1))) unsigned int*)(g), \
    (__attribute__((address_space(3))) unsigned int*)(l), 16, 0, 0)

// cpk u16 index for element (col, d): MFMA B-fragment order
__device__ __forceinline__ size_t cpk_idx(int col, int d) {
    int kk = d >> 5, r = d & 31, lg = r >> 3, j = r & 7;
    int nt = col >> 4, l15 = col & 15;
    return (size_t)((kk * 7 + nt) * 512) + lg * 128 + l15 * 8 + j;
}

__device__ __forceinline__ unsigned short bf16_rne(float x) {
    unsigned u = __float_as_uint(x);
    unsigned r = (u + 0x7fff + ((u >> 16) & 1)) >> 16;   // round-nearest-even
    return (unsigned short)r;
}

// ---- normalize centroids -> bf16 cpk; block 112 zeroes cnt/flagn ----
__global__ void k_norm_c(const float* __restrict__ c, unsigned short* __restrict__ cpk,
                         double* __restrict__ nc64, int* __restrict__ cnt,
                         int* __restrict__ flagn) {
    int col = blockIdx.x;
    int t = threadIdx.x;  // 128
    if (col == 112) {
        if (t < K_N) cnt[t] = 0;
        if (t == 0) *flagn = 0;
        return;
    }
    if (col >= K_N) {
        for (int d = t; d < D_N; d += 128) cpk[cpk_idx(col, d)] = 0;
        return;
    }
    const float* row = c + (size_t)col * D_N;
    double ss = 0.0;
    for (int d = t; d < D_N; d += 128) { double v = row[d]; ss += v * v; }
    __shared__ double red[2];
    for (int o = 32; o > 0; o >>= 1) ss += __shfl_down(ss, o);
    if ((t & 63) == 0) red[t >> 6] = ss;
    __syncthreads();
    double nc = fmax(sqrt(red[0] + red[1]), (double)EPS);
    if (t == 0) nc64[col] = nc;
    float inv = (float)(1.0 / nc);
    for (int d = t; d < D_N; d += 128)
        cpk[cpk_idx(col, d)] = bf16_rne(row[d] * inv);
}

// split 8 floats -> bf16 hi (trunc) + lo (rne of residual): a ≈ hi+lo to ~2^-17
__device__ __forceinline__ void splitA(float4 x0, float4 x1,
                                       short8& ah, short8& al, float& ss) {
    float xs[8] = {x0.x, x0.y, x0.z, x0.w, x1.x, x1.y, x1.z, x1.w};
#pragma unroll
    for (int j = 0; j < 8; j++) {
        float x = xs[j];
        unsigned xb = __float_as_uint(x);
        unsigned hb = xb & 0xffff0000u;
        float lf = x - __uint_as_float(hb);
        ah[j] = (short)(hb >> 16);
        al[j] = (short)bf16_rne(lf);
        ss = fmaf(x, x, ss);
    }
}

// ---- MFMA sims v10: all-B LDS + ALL A hoisted to regs (24KB/wave in flight);
// K-loop issues zero VMEM -> A-stream runs at full HBM depth.
__global__ __launch_bounds__(512) void k_main(
    const float* __restrict__ e, const unsigned short* __restrict__ cpk,
    float* __restrict__ out_nov, float* __restrict__ out_cls,
    unsigned* __restrict__ flags, int* __restrict__ flagn) {
    __shared__ unsigned short sB[84 * 512];   // 86016 B : all 7 B-tiles
    const int t = threadIdx.x;
    const int lane = t & 63;
    const int wid = t >> 6;                   // 8 waves
    const int l15 = lane & 15;
    const int lg = lane >> 4;
    const int rowbase = blockIdx.x * 128 + wid * 16;

    // stage all of B once (84 x 1KB chunks over 8 waves) — L2-hot source
    for (int c = wid; c < 84; c += 8)
        GLOAD_LDS((const char*)cpk + c * 1024 + lane * 16,
                  (char*)sB + c * 1024);

    const float* a0p = e + (size_t)(rowbase + l15) * D_N + lg * 8;

    // hoist ALL A loads: 24 float4 per thread, issued back-to-back (deep queue)
    float4 a[12][2];
#pragma unroll
    for (int kk = 0; kk < 12; kk++) {
        a[kk][0] = *(const float4*)(a0p + kk * 32);
        a[kk][1] = *(const float4*)(a0p + kk * 32 + 4);
    }

    f32x4 acc[7];
#pragma unroll
    for (int nt = 0; nt < 7; nt++) acc[nt] = f32x4{0.f, 0.f, 0.f, 0.f};
    float ss0 = 0.f;

    __syncthreads();   // B resident (A loads drain naturally via vmcnt-in-order)

#pragma unroll
    for (int kk = 0; kk < 12; kk++) {
        short8 ah0, al0;
        splitA(a[kk][0], a[kk][1], ah0, al0, ss0);
#pragma unroll
        for (int nt = 0; nt < 7; nt++) {
            short8 bh = *(const short8*)(sB + (kk * 7 + nt) * 512 + lane * 8);
            acc[nt] = __builtin_amdgcn_mfma_f32_16x16x32_bf16(ah0, bh, acc[nt], 0, 0, 0);
            acc[nt] = __builtin_amdgcn_mfma_f32_16x16x32_bf16(al0, bh, acc[nt], 0, 0, 0);
        }
    }

    // row sum-of-squares: lanes sharing l15 hold disjoint k-chunks
    ss0 += __shfl_xor(ss0, 16); ss0 += __shfl_xor(ss0, 32);
    const int rl = lg * 4 + (l15 & 3);
    float ssr0 = __shfl(ss0, rl);

    float b0 = -3e38f, b1 = -3e38f, b2 = -3e38f, b3 = -3e38f;
    float s0 = -3e38f, s1 = -3e38f, s2 = -3e38f, s3 = -3e38f;
    int i0 = 0, i1 = 0, i2 = 0, i3 = 0, j0 = 0, j1 = 0, j2 = 0, j3 = 0;
#pragma unroll
    for (int nt = 0; nt < 7; nt++) {
        int cl = nt * 16 + l15;
        bool valid = cl < K_N;
        float v;
        v = valid ? acc[nt][0] : -3e38f;
        if (v > b0) { s0 = b0; j0 = i0; b0 = v; i0 = cl; } else if (v > s0) { s0 = v; j0 = cl; }
        v = valid ? acc[nt][1] : -3e38f;
        if (v > b1) { s1 = b1; j1 = i1; b1 = v; i1 = cl; } else if (v > s1) { s1 = v; j1 = cl; }
        v = valid ? acc[nt][2] : -3e38f;
        if (v > b2) { s2 = b2; j2 = i2; b2 = v; i2 = cl; } else if (v > s2) { s2 = v; j2 = cl; }
        v = valid ? acc[nt][3] : -3e38f;
        if (v > b3) { s3 = b3; j3 = i3; b3 = v; i3 = cl; } else if (v > s3) { s3 = v; j3 = cl; }
    }
#pragma unroll
    for (int w = 1; w <= 8; w <<= 1) {
#define MRG(B, S, I, J)                                                        \
        {                                                                      \
            float ob = __shfl_xor(B, w), os = __shfl_xor(S, w);                \
            int obi = __shfl_xor(I, w), osi = __shfl_xor(J, w);                \
            if (ob > B) {                                                      \
                float ns; int nsi;                                             \
                if (B > os) { ns = B; nsi = I; } else { ns = os; nsi = osi; }  \
                B = ob; I = obi; S = ns; J = nsi;                              \
            } else if (ob > S) { S = ob; J = obi; }                            \
        }
        MRG(b0, s0, i0, j0) MRG(b1, s1, i1, j1) MRG(b2, s2, i2, j2) MRG(b3, s3, i3, j3)
#undef MRG
    }
    if (l15 < 4) {
        float bb = (l15 & 2) ? ((l15 & 1) ? b3 : b2) : ((l15 & 1) ? b1 : b0);
        float sv = (l15 & 2) ? ((l15 & 1) ? s3 : s2) : ((l15 & 1) ? s1 : s0);
        int bi   = (l15 & 2) ? ((l15 & 1) ? i3 : i2) : ((l15 & 1) ? i1 : i0);
        int si   = (l15 & 2) ? ((l15 & 1) ? j3 : j2) : ((l15 & 1) ? j1 : j0);
        int grow = rowbase + rl;
        float nrm = fmaxf(sqrtf(ssr0), EPS);
        float msim = bb / nrm;
        out_nov[grow] = 1.f - msim * msim;
        out_cls[grow] = (float)bi;
        if (bb - sv < FLAG_THR * nrm) {   // near-tie: fp64 re-resolve later
            int pos = atomicAdd(flagn, 1);
            flags[pos] = ((unsigned)grow << 14) | ((unsigned)bi << 7) | (unsigned)si;
        }
    }
}

// ---- cooperative fp64 refinement of flagged near-ties ----
__global__ void k_refine(const float* __restrict__ e, const float* __restrict__ c_raw,
                         const double* __restrict__ nc64, const int* __restrict__ flagn,
                         const unsigned* __restrict__ flags,
                         float* __restrict__ out_nov, float* __restrict__ out_cls) {
    int n = *flagn;
    int gw = (blockIdx.x * 256 + threadIdx.x) >> 6;
    int lane = threadIdx.x & 63;
    int nw = (gridDim.x * 256) >> 6;
    for (int i = gw; i < n; i += nw) {
        unsigned f = flags[i];
        int row = f >> 14, bi = (f >> 7) & 127, si = f & 127;
        const float* er = e + (size_t)row * D_N;
        const float* ca = c_raw + (size_t)bi * D_N;
        const float* cb = c_raw + (size_t)si * D_N;
        double d1 = 0, d2 = 0, ee = 0;
#pragma unroll
        for (int j = 0; j < 6; j++) {
            int d = lane * 6 + j;
            double ev = er[d];
            d1 += ev * (double)ca[d];
            d2 += ev * (double)cb[d];
            ee += ev * ev;
        }
#pragma unroll
        for (int w = 1; w <= 32; w <<= 1) {
            d1 += __shfl_xor(d1, w); d2 += __shfl_xor(d2, w); ee += __shfl_xor(ee, w);
        }
        if (lane == 0) {
            double v1 = d1 / nc64[bi], v2 = d2 / nc64[si];
            int k; double v;
            if (v2 > v1 || (v2 == v1 && si < bi)) { k = si; v = v2; } else { k = bi; v = v1; }
            double nrm = fmax(sqrt(ee), (double)EPS);
            double ms = v / nrm;
            out_nov[row] = (float)(1.0 - ms * ms);
            out_cls[row] = (float)k;
        }
    }
}

// ---- streaming segment sums + histogram (post-refine assignments) ----
__global__ __launch_bounds__(768) void k_accum(
    const float* __restrict__ e, const float* __restrict__ cls,
    int* __restrict__ parts, int* __restrict__ cnt) {
    __shared__ int sums[D_N * KSTR];          // 155,136 B
    __shared__ int scls[ROWS_PB];             // 4 KB
    __shared__ int h[K_N];                    // 400 B
    const int t = threadIdx.x;
    const int rg = t / D_N;                   // 0..1 (row group)
    const int d = t - rg * D_N;               // owned dim
    const size_t rbase = (size_t)blockIdx.x * ROWS_PB;

    for (int i = t; i < D_N * KSTR; i += 768) sums[i] = 0;
    if (t < K_N) h[t] = 0;
    __syncthreads();
    for (int i = t; i < ROWS_PB; i += 768) {
        int k = (int)cls[rbase + i];
        scls[i] = k;
        atomicAdd(&h[k], 1);
    }
    __syncthreads();
    if (t < K_N && h[t] > 0) atomicAdd(&cnt[t], h[t]);

    const float* eb = e + rbase * D_N;
    for (int g = 0; g < ROWS_PB; g += 16) {
        const int r0 = g + rg,      r1 = g + rg + 2,  r2 = g + rg + 4,  r3 = g + rg + 6;
        const int r4 = g + rg + 8,  r5 = g + rg + 10, r6 = g + rg + 12, r7 = g + rg + 14;
        float v0 = eb[(size_t)r0 * D_N + d]; float v1 = eb[(size_t)r1 * D_N + d];
        float v2 = eb[(size_t)r2 * D_N + d]; float v3 = eb[(size_t)r3 * D_N + d];
        float v4 = eb[(size_t)r4 * D_N + d]; float v5 = eb[(size_t)r5 * D_N + d];
        float v6 = eb[(size_t)r6 * D_N + d]; float v7 = eb[(size_t)r7 * D_N + d];
        atomicAdd(&sums[d * KSTR + scls[r0]], __float2int_rn(v0 * 65536.f));
        atomicAdd(&sums[d * KSTR + scls[r1]], __float2int_rn(v1 * 65536.f));
        atomicAdd(&sums[d * KSTR + scls[r2]], __float2int_rn(v2 * 65536.f));
        atomicAdd(&sums[d * KSTR + scls[r3]], __float2int_rn(v3 * 65536.f));
        atomicAdd(&sums[d * KSTR + scls[r4]], __float2int_rn(v4 * 65536.f));
        atomicAdd(&sums[d * KSTR + scls[r5]], __float2int_rn(v5 * 65536.f));
        atomicAdd(&sums[d * KSTR + scls[r6]], __float2int_rn(v6 * 65536.f));
        atomicAdd(&sums[d * KSTR + scls[r7]], __float2int_rn(v7 * 65536.f));
    }
    __syncthreads();

    int* pb = parts + (size_t)blockIdx.x * PART_N;
    for (int i = t; i < PART_N; i += 768) {
        int kq = i / D_N, dr = i - kq * D_N;
        pb[i] = sums[dr * KSTR + kq];
    }
}

// ---- deterministic reduce: 256 i32 partials -> centroids (+ counts out) ----
__global__ void k_reduce(const float* __restrict__ c_raw, const int* __restrict__ parts,
                         const int* __restrict__ cnt, const float* __restrict__ counts_in,
                         float* __restrict__ out_cent, float* __restrict__ out_cnts) {
    int idx = blockIdx.x * 256 + threadIdx.x;
    if (blockIdx.x == 0 && threadIdx.x < K_N)
        out_cnts[threadIdx.x] = counts_in[threadIdx.x] + (float)cnt[threadIdx.x];
    if (idx >= PART_N) return;
    long long s = 0;
#pragma unroll 8
    for (int b = 0; b < NBLK; b++) s += (long long)parts[(size_t)b * PART_N + idx];
    int k = idx / D_N;
    int n = cnt[k];
    float c0 = c_raw[idx];
    float mean = (float)((double)s / 65536.0 / (double)(n > 1 ? n : 1));
    out_cent[idx] = (n > 0) ? (MOM * c0 + (1.0f - MOM) * mean) : c0;
}

extern "C" void kernel_launch(void* const* d_in, const int* in_sizes, int n_in,
                              void* d_out, int out_size, void* d_ws, size_t ws_size,
                              hipStream_t stream) {
    const float* emb    = (const float*)d_in[0];
    const float* cen    = (const float*)d_in[1];
    const float* counts = (const float*)d_in[2];
    float* out = (float*)d_out;
    char* ws = (char*)d_ws;

    unsigned short* cpk   = (unsigned short*)(ws + OFF_CPK);
    double*         nc64  = (double*)(ws + OFF_NC64);
    int*            cnt   = (int*)(ws + OFF_CNT);
    int*            flagn = (int*)(ws + OFF_FLAGN);
    unsigned*       flags = (unsigned*)(ws + OFF_FLAGS);
    int*            parts = (int*)(ws + OFF_PARTS);

    float* out_nov  = out;
    float* out_cls  = out + B_N;
    float* out_cent = out + 2 * B_N;
    float* out_cnts = out + 2 * B_N + K_N * D_N;

    k_norm_c<<<113, 128, 0, stream>>>(cen, cpk, nc64, cnt, flagn);
    k_main<<<B_N / 128, 512, 0, stream>>>(emb, cpk, out_nov, out_cls, flags, flagn);
    k_refine<<<256, 256, 0, stream>>>(emb, cen, nc64, flagn, flags, out_nov, out_cls);
    k_accum<<<NBLK, 768, 0, stream>>>(emb, out_cls, parts, cnt);
    k_reduce<<<(PART_N + 255) / 256, 256, 0, stream>>>(cen, parts, cnt, counts,
                                                       out_cent, out_cnts);
}